// Round 3
// baseline (640.049 us; speedup 1.0000x reference)
//
#include <hip/hip_runtime.h>
#include <cmath>

// Problem constants (B=16, T=2048, D=1024 per reference setup_inputs)
constexpr int BATCH  = 16;
constexpr int T      = 2048;
constexpr int D      = 1024;
constexpr int NTOK   = BATCH * T;        // 32768 tokens
constexpr int NUM_MASK = 1433;           // int(2048 * 0.7)
constexpr int PCOLS  = 8;                // partial columns = N tiles (1024/128)

typedef __attribute__((ext_vector_type(8))) short short8;
typedef __attribute__((ext_vector_type(4))) float f32x4;

static __device__ __forceinline__ unsigned short bf16_rne(float f) {
  unsigned int u = __float_as_uint(f);
  u += 0x7fffu + ((u >> 16) & 1u);
  return (unsigned short)(u >> 16);
}
static __device__ __forceinline__ float bf16_to_f(unsigned short h) {
  return __uint_as_float(((unsigned int)h) << 16);
}
// 2 floats -> packed hi-bf16 dword + packed lo-bf16 dword (residual split)
static __device__ __forceinline__ void cvt2(float a, float b,
                                            unsigned int& hi, unsigned int& lo) {
  unsigned short ha = bf16_rne(a), hb = bf16_rne(b);
  unsigned short la = bf16_rne(a - bf16_to_f(ha));
  unsigned short lb = bf16_rne(b - bf16_to_f(hb));
  hi = (unsigned int)ha | ((unsigned int)hb << 16);
  lo = (unsigned int)la | ((unsigned int)lb << 16);
}

// async global->LDS, 16B per lane; LDS dest = wave-uniform base + lane*16
static __device__ __forceinline__ void dma16(const void* g, void* l) {
  __builtin_amdgcn_global_load_lds(
      (const __attribute__((address_space(1))) void*)g,
      (__attribute__((address_space(3))) void*)l, 16, 0, 0);
}

// K0: split W1 (fp32, 1024x1024) into bf16 hi/lo planes in PERMUTED
// fragment-order chunk layout: chunk (g=row/16, kt=k/32) is 1024 B,
// lane l=(q*16+c) holds 8 bf16 of (row=g*16+c, k=kt*32+q*8 .. +7) at l*16.
__global__ __launch_bounds__(256) void k_convW(
    const float* __restrict__ W1, uint4* __restrict__ Whp, uint4* __restrict__ Wlp)
{
  const int tid = blockIdx.x * 256 + threadIdx.x;   // 131072
  const int l  = tid & 63;
  const int kt = (tid >> 6) & 31;
  const int g  = tid >> 11;
  const int row = g * 16 + (l & 15);
  const int k   = kt * 32 + (l >> 4) * 8;
  const float4 f0 = *(const float4*)(W1 + (size_t)row * D + k);
  const float4 f1 = *(const float4*)(W1 + (size_t)row * D + k + 4);
  uint4 h, lo;
  cvt2(f0.x, f0.y, h.x, lo.x); cvt2(f0.z, f0.w, h.y, lo.y);
  cvt2(f1.x, f1.y, h.z, lo.z); cvt2(f1.z, f1.w, h.w, lo.w);
  Whp[tid] = h;
  Wlp[tid] = lo;
}

// K1: partial[token][ntile] = sum_{e in 128-tile} tanh(x·W1[e] + b1[e]) * w2[e]
// 3-pass split-bf16 MFMA (hh + lh + hl), 128x128 tile, BK=32, 4 waves (2x2 of 64x64).
// A: fp32 global load -> cvt -> permuted ds_write_b128 (2-way aliasing only).
// B: global_load_lds DMA from permuted Whp/Wlp -> fragment reads are lane*16
//    contiguous ds_read_b128 (conflict-free).
__global__ __launch_bounds__(256) void k_scores_mfma(
    const float* __restrict__ x,
    const unsigned short* __restrict__ Whp, const unsigned short* __restrict__ Wlp,
    const float* __restrict__ b1, const float* __restrict__ w2,
    float* __restrict__ partial)
{
  __shared__ __align__(16) unsigned short Ah[8 * 512];
  __shared__ __align__(16) unsigned short Al[8 * 512];
  __shared__ __align__(16) unsigned short Bh[8 * 512];
  __shared__ __align__(16) unsigned short Bl[8 * 512];
  __shared__ float red[128][2];

  const int bx = blockIdx.x;            // n tile 0..7
  const int by = blockIdx.y;            // m tile 0..255
  const int n0 = bx * 128;
  const int m0 = by * 128;
  const int t    = threadIdx.x;
  const int lane = t & 63;
  const int w    = t >> 6;              // wave 0..3
  const int wm   = (w >> 1) * 64;
  const int wn   = (w & 1) * 64;
  const int c    = lane & 15;
  const int q    = lane >> 4;

  // A staging role: row r (0..127), k-half h16 (16 elems)
  const int r  = t >> 1;
  const int hh = t & 1;
  const int cA = r & 15, gA = r >> 4;
  const float* aptr = x + (size_t)(m0 + r) * D + hh * 16;
  const int wo0 = gA * 512 + ((2 * hh) * 16 + cA) * 8;       // q = 2h
  const int wo1 = gA * 512 + ((2 * hh + 1) * 16 + cA) * 8;   // q = 2h+1

  // B DMA: wave w stages chunks 2w, 2w+1 of each plane per kt
  const int ch0 = 2 * w, ch1 = 2 * w + 1;
  const char* whB = (const char*)Whp;
  const char* wlB = (const char*)Wlp;
  const size_t bb0 = ((size_t)(n0 / 16 + ch0) * 32) * 1024 + lane * 16;
  const size_t bb1 = ((size_t)(n0 / 16 + ch1) * 32) * 1024 + lane * 16;

  f32x4 acc[4][4];
#pragma unroll
  for (int i = 0; i < 4; ++i)
#pragma unroll
    for (int j = 0; j < 4; ++j)
      acc[i][j] = (f32x4){0.f, 0.f, 0.f, 0.f};

  for (int kt = 0; kt < 32; ++kt) {
    const float4 f0 = *(const float4*)(aptr + kt * 32 + 0);
    const float4 f1 = *(const float4*)(aptr + kt * 32 + 4);
    const float4 f2 = *(const float4*)(aptr + kt * 32 + 8);
    const float4 f3 = *(const float4*)(aptr + kt * 32 + 12);
    uint4 h0, l0, h1, l1;
    cvt2(f0.x, f0.y, h0.x, l0.x); cvt2(f0.z, f0.w, h0.y, l0.y);
    cvt2(f1.x, f1.y, h0.z, l0.z); cvt2(f1.z, f1.w, h0.w, l0.w);
    cvt2(f2.x, f2.y, h1.x, l1.x); cvt2(f2.z, f2.w, h1.y, l1.y);
    cvt2(f3.x, f3.y, h1.z, l1.z); cvt2(f3.z, f3.w, h1.w, l1.w);

    __syncthreads();   // previous iter's fragment reads done
    *(uint4*)&Ah[wo0] = h0;  *(uint4*)&Ah[wo1] = h1;
    *(uint4*)&Al[wo0] = l0;  *(uint4*)&Al[wo1] = l1;
    dma16(whB + bb0 + kt * 1024, &Bh[ch0 * 512]);
    dma16(whB + bb1 + kt * 1024, &Bh[ch1 * 512]);
    dma16(wlB + bb0 + kt * 1024, &Bl[ch0 * 512]);
    dma16(wlB + bb1 + kt * 1024, &Bl[ch1 * 512]);
    __syncthreads();   // LDS writes + DMA visible

    short8 avh[4], avl[4], bvh[4], bvl[4];
#pragma unroll
    for (int i = 0; i < 4; ++i) {
      const int ao = ((wm >> 4) + i) * 512 + lane * 8;
      const int bo = ((wn >> 4) + i) * 512 + lane * 8;
      avh[i] = *(const short8*)&Ah[ao];
      avl[i] = *(const short8*)&Al[ao];
      bvh[i] = *(const short8*)&Bh[bo];
      bvl[i] = *(const short8*)&Bl[bo];
    }
#pragma unroll
    for (int i = 0; i < 4; ++i)
#pragma unroll
      for (int j = 0; j < 4; ++j)
        acc[i][j] = __builtin_amdgcn_mfma_f32_16x16x32_bf16(avh[i], bvh[j], acc[i][j], 0, 0, 0);
#pragma unroll
    for (int i = 0; i < 4; ++i)
#pragma unroll
      for (int j = 0; j < 4; ++j)
        acc[i][j] = __builtin_amdgcn_mfma_f32_16x16x32_bf16(avl[i], bvh[j], acc[i][j], 0, 0, 0);
#pragma unroll
    for (int i = 0; i < 4; ++i)
#pragma unroll
      for (int j = 0; j < 4; ++j)
        acc[i][j] = __builtin_amdgcn_mfma_f32_16x16x32_bf16(avh[i], bvl[j], acc[i][j], 0, 0, 0);
  }

  // epilogue (verified in R2): n = n0+wn+j*16+c ; m = m0+wm+i*16+q*4+reg
  float b1v[4], w2v[4];
#pragma unroll
  for (int j = 0; j < 4; ++j) {
    const int n = n0 + wn + j * 16 + c;
    b1v[j] = b1[n];
    w2v[j] = w2[n];
  }
  float rs[4][4];
#pragma unroll
  for (int i = 0; i < 4; ++i)
#pragma unroll
    for (int rr = 0; rr < 4; ++rr) {
      float s = 0.f;
#pragma unroll
      for (int j = 0; j < 4; ++j) {
        const float z = acc[i][j][rr] + b1v[j];
        const float th = 1.f - 2.f / (__expf(2.f * z) + 1.f);   // tanh via fast exp
        s += th * w2v[j];
      }
      rs[i][rr] = s;
    }
#pragma unroll
  for (int off = 1; off < 16; off <<= 1)
#pragma unroll
    for (int i = 0; i < 4; ++i)
#pragma unroll
      for (int rr = 0; rr < 4; ++rr)
        rs[i][rr] += __shfl_xor(rs[i][rr], off);
  if (c == 0) {
#pragma unroll
    for (int i = 0; i < 4; ++i)
#pragma unroll
      for (int rr = 0; rr < 4; ++rr)
        red[wm + i * 16 + q * 4 + rr][w & 1] = rs[i][rr];
  }
  __syncthreads();
  if (t < 128)
    partial[(size_t)(m0 + t) * PCOLS + bx] = red[t][0] + red[t][1];
}

// K2: per batch — s = sum(partial)+b2, softmax, exact stable rank, mask.
// Fused (scores live in LDS). 1024 threads, 16 blocks.
__global__ __launch_bounds__(1024) void k_softmax_mask(
    const float* __restrict__ partial, const float* __restrict__ b2,
    float* __restrict__ mw, float* __restrict__ out_w)
{
  const int b = blockIdx.x;
  const int t = threadIdx.x;
  __shared__ __align__(16) float s[T];
  __shared__ float red[18];

  const float b2v = b2[0];
  for (int i = t; i < T; i += 1024) {
    const float* p = partial + (size_t)(b * T + i) * PCOLS;
    float a = 0.f;
#pragma unroll
    for (int j = 0; j < PCOLS; ++j) a += p[j];
    s[i] = a + b2v;
  }
  __syncthreads();

  const int wid = t >> 6, ln = t & 63;
  float m = fmaxf(s[t], s[t + 1024]);
  for (int off = 32; off > 0; off >>= 1) m = fmaxf(m, __shfl_down(m, off));
  if (ln == 0) red[wid] = m;
  __syncthreads();
  if (t == 0) {
    float mm = red[0];
    for (int i = 1; i < 16; ++i) mm = fmaxf(mm, red[i]);
    red[16] = mm;
  }
  __syncthreads();
  const float M = red[16];

  float zs = expf(s[t] - M) + expf(s[t + 1024] - M);
  for (int off = 32; off > 0; off >>= 1) zs += __shfl_down(zs, off);
  if (ln == 0) red[wid] = zs;
  __syncthreads();
  if (t == 0) {
    float zz = 0.f;
    for (int i = 0; i < 16; ++i) zz += red[i];
    red[17] = zz;
  }
  __syncthreads();
  const float Z = red[17];

  const float4* s4 = (const float4*)s;
#pragma unroll
  for (int ii = 0; ii < 2; ++ii) {
    const int i = t + ii * 1024;
    const float si = s[i];
    int r = 0;
#pragma unroll 4
    for (int j4 = 0; j4 < T / 4; ++j4) {
      const float4 v = s4[j4];
      const int jb = j4 * 4;
      r += (v.x < si) || ((v.x == si) && (jb + 0 < i));
      r += (v.y < si) || ((v.y == si) && (jb + 1 < i));
      r += (v.z < si) || ((v.z == si) && (jb + 2 < i));
      r += (v.w < si) || ((v.w == si) && (jb + 3 < i));
    }
    const float wv = (r < NUM_MASK) ? 0.f : expf(si - M) / Z;
    mw[b * T + i]    = wv;
    out_w[b * T + i] = wv;
  }
}

// K3: out[b,t,d] = x[b,t,d] * mw[b,t], float4 grid-stride
__global__ __launch_bounds__(256) void k_output(
    const float4* __restrict__ x4, const float* __restrict__ mw,
    float4* __restrict__ out4)
{
  const int n4 = NTOK * (D / 4);
  int idx = blockIdx.x * blockDim.x + threadIdx.x;
  const int stride = gridDim.x * blockDim.x;
  for (; idx < n4; idx += stride) {
    float4 v = x4[idx];
    const float wv = mw[idx >> 8];
    v.x *= wv; v.y *= wv; v.z *= wv; v.w *= wv;
    out4[idx] = v;
  }
}

extern "C" void kernel_launch(void* const* d_in, const int* in_sizes, int n_in,
                              void* d_out, int out_size, void* d_ws, size_t ws_size,
                              hipStream_t stream) {
  const float* x  = (const float*)d_in[0];
  const float* W1 = (const float*)d_in[1];
  const float* b1 = (const float*)d_in[2];
  const float* w2 = (const float*)d_in[3];
  const float* b2 = (const float*)d_in[4];
  float* out = (float*)d_out;

  // workspace (~5.2 MB, fully rewritten every launch)
  unsigned short* Whp = (unsigned short*)d_ws;            // 2 MB (permuted)
  unsigned short* Wlp = Whp + (size_t)D * D;              // 2 MB (permuted)
  float* partial = (float*)(Wlp + (size_t)D * D);         // NTOK*8*4 = 1 MB
  float* mw      = partial + (size_t)NTOK * PCOLS;        // 128 KB

  hipLaunchKernelGGL(k_convW, dim3((D * D / 8) / 256), dim3(256), 0, stream,
                     W1, (uint4*)Whp, (uint4*)Wlp);
  hipLaunchKernelGGL(k_scores_mfma, dim3(8, NTOK / 128), dim3(256), 0, stream,
                     x, Whp, Wlp, b1, w2, partial);
  hipLaunchKernelGGL(k_softmax_mask, dim3(BATCH), dim3(1024), 0, stream,
                     partial, b2, mw, out + (size_t)NTOK * D);
  hipLaunchKernelGGL(k_output, dim3(8192), dim3(256), 0, stream,
                     (const float4*)x, mw, (float4*)out);
}

// Round 4
// 509.742 us; speedup vs baseline: 1.2556x; 1.2556x over previous
//
#include <hip/hip_runtime.h>
#include <cmath>

// Problem constants (B=16, T=2048, D=1024 per reference setup_inputs)
constexpr int BATCH  = 16;
constexpr int T      = 2048;
constexpr int D      = 1024;
constexpr int NTOK   = BATCH * T;        // 32768 tokens
constexpr int NUM_MASK = 1433;           // int(2048 * 0.7)
constexpr int PCOLS  = 8;                // partial columns = N tiles (1024/128)
constexpr int MAXLIST = 1024;            // band-row capacity (expected ~735 worst)
#define EPS_BAND 0.02f                   // ~15 sigma of 1-pass score noise

typedef __attribute__((ext_vector_type(8))) short short8;
typedef __attribute__((ext_vector_type(4))) float f32x4;

static __device__ __forceinline__ unsigned short bf16_rne(float f) {
  unsigned int u = __float_as_uint(f);
  u += 0x7fffu + ((u >> 16) & 1u);
  return (unsigned short)(u >> 16);
}
static __device__ __forceinline__ float bf16_to_f(unsigned short h) {
  return __uint_as_float(((unsigned int)h) << 16);
}
// 2 floats -> packed hi-bf16 dword + packed lo-bf16 dword (residual split)
static __device__ __forceinline__ void cvt2(float a, float b,
                                            unsigned int& hi, unsigned int& lo) {
  unsigned short ha = bf16_rne(a), hb = bf16_rne(b);
  unsigned short la = bf16_rne(a - bf16_to_f(ha));
  unsigned short lb = bf16_rne(b - bf16_to_f(hb));
  hi = (unsigned int)ha | ((unsigned int)hb << 16);
  lo = (unsigned int)la | ((unsigned int)lb << 16);
}
// 2 floats -> packed hi-bf16 only (1-pass path)
static __device__ __forceinline__ unsigned int cvt2h(float a, float b) {
  return (unsigned int)bf16_rne(a) | ((unsigned int)bf16_rne(b) << 16);
}

// async global->LDS, 16B per lane; LDS dest = wave-uniform base + lane*16
static __device__ __forceinline__ void dma16(const void* g, void* l) {
  __builtin_amdgcn_global_load_lds(
      (const __attribute__((address_space(1))) void*)g,
      (__attribute__((address_space(3))) void*)l, 16, 0, 0);
}

// K0: split W1 into bf16 hi/lo planes in PERMUTED fragment-order chunk layout
// (verified R3): chunk (g=row/16, kt=k/32) is 1024 B, lane l=(q*16+c) holds
// 8 bf16 of (row=g*16+c, k=kt*32+(l>>4)*8 ..+7) at l*16.
__global__ __launch_bounds__(256) void k_convW(
    const float* __restrict__ W1, uint4* __restrict__ Whp, uint4* __restrict__ Wlp)
{
  const int tid = blockIdx.x * 256 + threadIdx.x;   // 131072
  const int l  = tid & 63;
  const int kt = (tid >> 6) & 31;
  const int g  = tid >> 11;
  const int row = g * 16 + (l & 15);
  const int k   = kt * 32 + (l >> 4) * 8;
  const float4 f0 = *(const float4*)(W1 + (size_t)row * D + k);
  const float4 f1 = *(const float4*)(W1 + (size_t)row * D + k + 4);
  uint4 h, lo;
  cvt2(f0.x, f0.y, h.x, lo.x); cvt2(f0.z, f0.w, h.y, lo.y);
  cvt2(f1.x, f1.y, h.z, lo.z); cvt2(f1.z, f1.w, h.w, lo.w);
  Whp[tid] = h;
  Wlp[tid] = lo;
}

// K1: 1-pass bf16 MFMA GEMM over all 32768 tokens -> partial[token][ntile].
// Same verified structure/layout as R3, hi plane only (16 MFMA / kt).
__global__ __launch_bounds__(256) void k_gemm1(
    const float* __restrict__ x, const unsigned short* __restrict__ Whp,
    const float* __restrict__ b1, const float* __restrict__ w2,
    float* __restrict__ partial)
{
  __shared__ __align__(16) unsigned short Ah[8 * 512];
  __shared__ __align__(16) unsigned short Bh[8 * 512];
  __shared__ float red[128][2];

  const int bx = blockIdx.x;            // n tile 0..7
  const int by = blockIdx.y;            // m tile 0..255
  const int n0 = bx * 128;
  const int m0 = by * 128;
  const int t    = threadIdx.x;
  const int lane = t & 63;
  const int w    = t >> 6;
  const int wm   = (w >> 1) * 64;
  const int wn   = (w & 1) * 64;
  const int c    = lane & 15;
  const int q    = lane >> 4;

  const int r  = t >> 1;
  const int hh = t & 1;
  const int cA = r & 15, gA = r >> 4;
  const float* aptr = x + (size_t)(m0 + r) * D + hh * 16;
  const int wo0 = gA * 512 + ((2 * hh) * 16 + cA) * 8;
  const int wo1 = gA * 512 + ((2 * hh + 1) * 16 + cA) * 8;

  const int ch0 = 2 * w, ch1 = 2 * w + 1;
  const char* whB = (const char*)Whp;
  const size_t bb0 = ((size_t)(n0 / 16 + ch0) * 32) * 1024 + lane * 16;
  const size_t bb1 = ((size_t)(n0 / 16 + ch1) * 32) * 1024 + lane * 16;

  f32x4 acc[4][4];
#pragma unroll
  for (int i = 0; i < 4; ++i)
#pragma unroll
    for (int j = 0; j < 4; ++j)
      acc[i][j] = (f32x4){0.f, 0.f, 0.f, 0.f};

  for (int kt = 0; kt < 32; ++kt) {
    const float4 f0 = *(const float4*)(aptr + kt * 32 + 0);
    const float4 f1 = *(const float4*)(aptr + kt * 32 + 4);
    const float4 f2 = *(const float4*)(aptr + kt * 32 + 8);
    const float4 f3 = *(const float4*)(aptr + kt * 32 + 12);
    uint4 h0, h1;
    h0.x = cvt2h(f0.x, f0.y); h0.y = cvt2h(f0.z, f0.w);
    h0.z = cvt2h(f1.x, f1.y); h0.w = cvt2h(f1.z, f1.w);
    h1.x = cvt2h(f2.x, f2.y); h1.y = cvt2h(f2.z, f2.w);
    h1.z = cvt2h(f3.x, f3.y); h1.w = cvt2h(f3.z, f3.w);

    __syncthreads();
    *(uint4*)&Ah[wo0] = h0;  *(uint4*)&Ah[wo1] = h1;
    dma16(whB + bb0 + kt * 1024, &Bh[ch0 * 512]);
    dma16(whB + bb1 + kt * 1024, &Bh[ch1 * 512]);
    __syncthreads();

    short8 avh[4], bvh[4];
#pragma unroll
    for (int i = 0; i < 4; ++i) {
      avh[i] = *(const short8*)&Ah[((wm >> 4) + i) * 512 + lane * 8];
      bvh[i] = *(const short8*)&Bh[((wn >> 4) + i) * 512 + lane * 8];
    }
#pragma unroll
    for (int i = 0; i < 4; ++i)
#pragma unroll
      for (int j = 0; j < 4; ++j)
        acc[i][j] = __builtin_amdgcn_mfma_f32_16x16x32_bf16(avh[i], bvh[j], acc[i][j], 0, 0, 0);
  }

  // epilogue (verified R2/R3): n = n0+wn+j*16+c ; m = m0+wm+i*16+q*4+reg
  float b1v[4], w2v[4];
#pragma unroll
  for (int j = 0; j < 4; ++j) {
    const int n = n0 + wn + j * 16 + c;
    b1v[j] = b1[n];
    w2v[j] = w2[n];
  }
  float rs[4][4];
#pragma unroll
  for (int i = 0; i < 4; ++i)
#pragma unroll
    for (int rr = 0; rr < 4; ++rr) {
      float s = 0.f;
#pragma unroll
      for (int j = 0; j < 4; ++j) {
        const float z = acc[i][j][rr] + b1v[j];
        const float th = 1.f - 2.f / (__expf(2.f * z) + 1.f);
        s += th * w2v[j];
      }
      rs[i][rr] = s;
    }
#pragma unroll
  for (int off = 1; off < 16; off <<= 1)
#pragma unroll
    for (int i = 0; i < 4; ++i)
#pragma unroll
      for (int rr = 0; rr < 4; ++rr)
        rs[i][rr] += __shfl_xor(rs[i][rr], off);
  if (c == 0) {
#pragma unroll
    for (int i = 0; i < 4; ++i)
#pragma unroll
      for (int rr = 0; rr < 4; ++rr)
        red[wm + i * 16 + q * 4 + rr][w & 1] = rs[i][rr];
  }
  __syncthreads();
  if (t < 128)
    partial[(size_t)(m0 + t) * PCOLS + bx] = red[t][0] + red[t][1];
}

// K2: per batch — s = sum(partial)+b2 -> s_buf, softmax stats M,Z; init counters.
__global__ __launch_bounds__(256) void k_stat(
    const float* __restrict__ partial, const float* __restrict__ b2,
    float* __restrict__ s_buf, float* __restrict__ Mbuf, float* __restrict__ Zbuf,
    int* __restrict__ Dcnt, int* __restrict__ cnt_total, int* __restrict__ list)
{
  const int b = blockIdx.x;
  const int t = threadIdx.x;
  __shared__ __align__(16) float s[T];
  __shared__ float red[8];

  if (t == 0) Dcnt[b] = 0;
  if (b == 0) {
    if (t == 0) cnt_total[0] = 0;
    for (int i = t; i < MAXLIST; i += 256) list[i] = 0;
  }

  const float b2v = b2[0];
  for (int i = t; i < T; i += 256) {
    const float* p = partial + (size_t)(b * T + i) * PCOLS;
    float a = 0.f;
#pragma unroll
    for (int j = 0; j < PCOLS; ++j) a += p[j];
    const float v = a + b2v;
    s[i] = v;
    s_buf[b * T + i] = v;
  }
  __syncthreads();

  float m = -INFINITY;
  for (int i = t; i < T; i += 256) m = fmaxf(m, s[i]);
  for (int off = 32; off > 0; off >>= 1) m = fmaxf(m, __shfl_down(m, off));
  if ((t & 63) == 0) red[t >> 6] = m;
  __syncthreads();
  if (t == 0) {
    float mm = -INFINITY;
    for (int i = 0; i < 4; ++i) mm = fmaxf(mm, red[i]);
    red[4] = mm;
  }
  __syncthreads();
  m = red[4];
  __syncthreads();

  float zs = 0.f;
  for (int i = t; i < T; i += 256) zs += expf(s[i] - m);
  for (int off = 32; off > 0; off >>= 1) zs += __shfl_down(zs, off);
  if ((t & 63) == 0) red[t >> 6] = zs;
  __syncthreads();
  if (t == 0) {
    float zz = 0.f;
    for (int i = 0; i < 4; ++i) zz += red[i];
    Mbuf[b] = m;
    Zbuf[b] = zz;
  }
}

// K3: exact stable rank on noisy scores; rank==NUM_MASK token publishes cut.
__global__ __launch_bounds__(256) void k_rank(
    const float* __restrict__ s_buf, float* __restrict__ cutbuf)
{
  const int b  = blockIdx.y;
  const int i0 = blockIdx.x * 256;
  const int t  = threadIdx.x;
  __shared__ __align__(16) float s[T];
  for (int i = t; i < T; i += 256) s[i] = s_buf[b * T + i];
  __syncthreads();

  const int i = i0 + t;
  const float si = s[i];
  int r = 0;
  const float4* s4 = (const float4*)s;
#pragma unroll 4
  for (int j4 = 0; j4 < T / 4; ++j4) {
    const float4 v = s4[j4];
    const int jb = j4 * 4;
    r += (v.x < si) || ((v.x == si) && (jb + 0 < i));
    r += (v.y < si) || ((v.y == si) && (jb + 1 < i));
    r += (v.z < si) || ((v.z == si) && (jb + 2 < i));
    r += (v.w < si) || ((v.w == si) && (jb + 3 < i));
  }
  if (r == NUM_MASK) cutbuf[b] = si;   // exactly one token per batch
}

// K4: classify tokens: definite-masked / definite-kept / band (append to list).
__global__ __launch_bounds__(256) void k_band(
    const float* __restrict__ s_buf, const float* __restrict__ Mbuf,
    const float* __restrict__ Zbuf, const float* __restrict__ cutbuf,
    int* __restrict__ Dcnt, int* __restrict__ cnt_total, int* __restrict__ list,
    float* __restrict__ mw, float* __restrict__ out_w)
{
  const int b = blockIdx.y;
  const int i = blockIdx.x * 256 + threadIdx.x;
  const float si  = s_buf[b * T + i];
  const float cut = cutbuf[b];
  const float wv  = expf(si - Mbuf[b]) / Zbuf[b];
  float mv;
  if (si <= cut - EPS_BAND) {
    mv = 0.f;
    atomicAdd(&Dcnt[b], 1);
  } else {
    mv = wv;                                  // tentative keep; k_fix may zero
    if (si < cut + EPS_BAND) {
      const int slot = atomicAdd(cnt_total, 1);
      if (slot < MAXLIST) list[slot] = (b << 16) | i;
    }
  }
  mw[b * T + i]    = mv;
  out_w[b * T + i] = mv;
}

// K5: 3-pass split-bf16 MFMA (verified R3) over the gathered band rows only.
__global__ __launch_bounds__(256) void k_gemm2(
    const float* __restrict__ x, const int* __restrict__ list,
    const unsigned short* __restrict__ Whp, const unsigned short* __restrict__ Wlp,
    const float* __restrict__ b1, const float* __restrict__ w2,
    float* __restrict__ partial2)
{
  __shared__ __align__(16) unsigned short Ah[8 * 512];
  __shared__ __align__(16) unsigned short Al[8 * 512];
  __shared__ __align__(16) unsigned short Bh[8 * 512];
  __shared__ __align__(16) unsigned short Bl[8 * 512];
  __shared__ float red[128][2];

  const int bx = blockIdx.x;
  const int by = blockIdx.y;            // 0..7 (1024 rows)
  const int n0 = bx * 128;
  const int m0 = by * 128;
  const int t    = threadIdx.x;
  const int lane = t & 63;
  const int w    = t >> 6;
  const int wm   = (w >> 1) * 64;
  const int wn   = (w & 1) * 64;
  const int c    = lane & 15;
  const int q    = lane >> 4;

  const int r  = t >> 1;
  const int hh = t & 1;
  const int cA = r & 15, gA = r >> 4;
  const int entry = list[m0 + r];       // 0 for unused slots -> x row 0 (harmless)
  const float* aptr = x + ((size_t)(entry >> 16) * T + (entry & 0xFFFF)) * D + hh * 16;
  const int wo0 = gA * 512 + ((2 * hh) * 16 + cA) * 8;
  const int wo1 = gA * 512 + ((2 * hh + 1) * 16 + cA) * 8;

  const int ch0 = 2 * w, ch1 = 2 * w + 1;
  const char* whB = (const char*)Whp;
  const char* wlB = (const char*)Wlp;
  const size_t bb0 = ((size_t)(n0 / 16 + ch0) * 32) * 1024 + lane * 16;
  const size_t bb1 = ((size_t)(n0 / 16 + ch1) * 32) * 1024 + lane * 16;

  f32x4 acc[4][4];
#pragma unroll
  for (int i = 0; i < 4; ++i)
#pragma unroll
    for (int j = 0; j < 4; ++j)
      acc[i][j] = (f32x4){0.f, 0.f, 0.f, 0.f};

  for (int kt = 0; kt < 32; ++kt) {
    const float4 f0 = *(const float4*)(aptr + kt * 32 + 0);
    const float4 f1 = *(const float4*)(aptr + kt * 32 + 4);
    const float4 f2 = *(const float4*)(aptr + kt * 32 + 8);
    const float4 f3 = *(const float4*)(aptr + kt * 32 + 12);
    uint4 h0, l0, h1, l1;
    cvt2(f0.x, f0.y, h0.x, l0.x); cvt2(f0.z, f0.w, h0.y, l0.y);
    cvt2(f1.x, f1.y, h0.z, l0.z); cvt2(f1.z, f1.w, h0.w, l0.w);
    cvt2(f2.x, f2.y, h1.x, l1.x); cvt2(f2.z, f2.w, h1.y, l1.y);
    cvt2(f3.x, f3.y, h1.z, l1.z); cvt2(f3.z, f3.w, h1.w, l1.w);

    __syncthreads();
    *(uint4*)&Ah[wo0] = h0;  *(uint4*)&Ah[wo1] = h1;
    *(uint4*)&Al[wo0] = l0;  *(uint4*)&Al[wo1] = l1;
    dma16(whB + bb0 + kt * 1024, &Bh[ch0 * 512]);
    dma16(whB + bb1 + kt * 1024, &Bh[ch1 * 512]);
    dma16(wlB + bb0 + kt * 1024, &Bl[ch0 * 512]);
    dma16(wlB + bb1 + kt * 1024, &Bl[ch1 * 512]);
    __syncthreads();

    short8 avh[4], avl[4], bvh[4], bvl[4];
#pragma unroll
    for (int i = 0; i < 4; ++i) {
      const int ao = ((wm >> 4) + i) * 512 + lane * 8;
      const int bo = ((wn >> 4) + i) * 512 + lane * 8;
      avh[i] = *(const short8*)&Ah[ao];
      avl[i] = *(const short8*)&Al[ao];
      bvh[i] = *(const short8*)&Bh[bo];
      bvl[i] = *(const short8*)&Bl[bo];
    }
#pragma unroll
    for (int i = 0; i < 4; ++i)
#pragma unroll
      for (int j = 0; j < 4; ++j)
        acc[i][j] = __builtin_amdgcn_mfma_f32_16x16x32_bf16(avh[i], bvh[j], acc[i][j], 0, 0, 0);
#pragma unroll
    for (int i = 0; i < 4; ++i)
#pragma unroll
      for (int j = 0; j < 4; ++j)
        acc[i][j] = __builtin_amdgcn_mfma_f32_16x16x32_bf16(avl[i], bvh[j], acc[i][j], 0, 0, 0);
#pragma unroll
    for (int i = 0; i < 4; ++i)
#pragma unroll
      for (int j = 0; j < 4; ++j)
        acc[i][j] = __builtin_amdgcn_mfma_f32_16x16x32_bf16(avh[i], bvl[j], acc[i][j], 0, 0, 0);
  }

  float b1v[4], w2v[4];
#pragma unroll
  for (int j = 0; j < 4; ++j) {
    const int n = n0 + wn + j * 16 + c;
    b1v[j] = b1[n];
    w2v[j] = w2[n];
  }
  float rs[4][4];
#pragma unroll
  for (int i = 0; i < 4; ++i)
#pragma unroll
    for (int rr = 0; rr < 4; ++rr) {
      float s = 0.f;
#pragma unroll
      for (int j = 0; j < 4; ++j) {
        const float z = acc[i][j][rr] + b1v[j];
        const float th = 1.f - 2.f / (__expf(2.f * z) + 1.f);
        s += th * w2v[j];
      }
      rs[i][rr] = s;
    }
#pragma unroll
  for (int off = 1; off < 16; off <<= 1)
#pragma unroll
    for (int i = 0; i < 4; ++i)
#pragma unroll
      for (int rr = 0; rr < 4; ++rr)
        rs[i][rr] += __shfl_xor(rs[i][rr], off);
  if (c == 0) {
#pragma unroll
    for (int i = 0; i < 4; ++i)
#pragma unroll
      for (int rr = 0; rr < 4; ++rr)
        red[wm + i * 16 + q * 4 + rr][w & 1] = rs[i][rr];
  }
  __syncthreads();
  if (t < 128)
    partial2[(size_t)(m0 + t) * PCOLS + bx] = red[t][0] + red[t][1];
}

// K6: per batch — exact band-internal stable rank; zero the (NUM_MASK - D) smallest.
__global__ __launch_bounds__(256) void k_fix(
    const float* __restrict__ partial2, const int* __restrict__ list,
    const int* __restrict__ cnt_total, const int* __restrict__ Dcnt,
    float* __restrict__ mw, float* __restrict__ out_w)
{
  const int b = blockIdx.x;
  const int t = threadIdx.x;
  __shared__ int   ltok[256];
  __shared__ float ls2[256];
  __shared__ int   lcnt;
  if (t == 0) lcnt = 0;
  __syncthreads();

  const int n = min(cnt_total[0], MAXLIST);
  for (int s = t; s < n; s += 256) {
    const int e = list[s];
    if ((e >> 16) == b) {
      const int p = atomicAdd(&lcnt, 1);
      if (p < 256) {
        float v = 0.f;
#pragma unroll
        for (int j = 0; j < PCOLS; ++j) v += partial2[(size_t)s * PCOLS + j];
        ltok[p] = e & 0xFFFF;
        ls2[p]  = v;
      }
    }
  }
  __syncthreads();
  const int c    = min(lcnt, 256);
  const int need = NUM_MASK - Dcnt[b];

  for (int idx = t; idx < c; idx += 256) {
    const float si = ls2[idx];
    const int   ti = ltok[idx];
    int r = 0;
    for (int j = 0; j < c; ++j)
      r += (ls2[j] < si) || ((ls2[j] == si) && (ltok[j] < ti));
    if (r < need) {
      mw[b * T + ti]    = 0.f;
      out_w[b * T + ti] = 0.f;
    }
  }
}

// K7: out[b,t,d] = x[b,t,d] * mw[b,t], float4 grid-stride
__global__ __launch_bounds__(256) void k_output(
    const float4* __restrict__ x4, const float* __restrict__ mw,
    float4* __restrict__ out4)
{
  const int n4 = NTOK * (D / 4);
  int idx = blockIdx.x * blockDim.x + threadIdx.x;
  const int stride = gridDim.x * blockDim.x;
  for (; idx < n4; idx += stride) {
    float4 v = x4[idx];
    const float wv = mw[idx >> 8];
    v.x *= wv; v.y *= wv; v.z *= wv; v.w *= wv;
    out4[idx] = v;
  }
}

extern "C" void kernel_launch(void* const* d_in, const int* in_sizes, int n_in,
                              void* d_out, int out_size, void* d_ws, size_t ws_size,
                              hipStream_t stream) {
  const float* x  = (const float*)d_in[0];
  const float* W1 = (const float*)d_in[1];
  const float* b1 = (const float*)d_in[2];
  const float* w2 = (const float*)d_in[3];
  const float* b2 = (const float*)d_in[4];
  float* out = (float*)d_out;
  float* out_w = out + (size_t)NTOK * D;

  // workspace (~5.4 MB)
  unsigned short* Whp = (unsigned short*)d_ws;            // 2 MB (permuted hi)
  unsigned short* Wlp = Whp + (size_t)D * D;              // 2 MB (permuted lo)
  float* partial  = (float*)(Wlp + (size_t)D * D);        // 1 MB
  float* s_buf    = partial + (size_t)NTOK * PCOLS;       // 128 KB
  float* mw       = s_buf + NTOK;                         // 128 KB
  float* partial2 = mw + NTOK;                            // 32 KB
  float* Mbuf     = partial2 + (size_t)MAXLIST * PCOLS;   // 16
  float* Zbuf     = Mbuf + BATCH;                         // 16
  float* cutbuf   = Zbuf + BATCH;                         // 16
  int*   Dcnt     = (int*)(cutbuf + BATCH);               // 16
  int*   cnt_total= Dcnt + BATCH;                         // 1 (+pad)
  int*   list     = cnt_total + 16;                       // 1024 ints

  hipLaunchKernelGGL(k_convW, dim3((D * D / 8) / 256), dim3(256), 0, stream,
                     W1, (uint4*)Whp, (uint4*)Wlp);
  hipLaunchKernelGGL(k_gemm1, dim3(8, NTOK / 128), dim3(256), 0, stream,
                     x, Whp, b1, w2, partial);
  hipLaunchKernelGGL(k_stat, dim3(BATCH), dim3(256), 0, stream,
                     partial, b2, s_buf, Mbuf, Zbuf, Dcnt, cnt_total, list);
  hipLaunchKernelGGL(k_rank, dim3(T / 256, BATCH), dim3(256), 0, stream,
                     s_buf, cutbuf);
  hipLaunchKernelGGL(k_band, dim3(T / 256, BATCH), dim3(256), 0, stream,
                     s_buf, Mbuf, Zbuf, cutbuf, Dcnt, cnt_total, list, mw, out_w);
  hipLaunchKernelGGL(k_gemm2, dim3(8, MAXLIST / 128), dim3(256), 0, stream,
                     x, list, Whp, Wlp, b1, w2, partial2);
  hipLaunchKernelGGL(k_fix, dim3(BATCH), dim3(256), 0, stream,
                     partial2, list, cnt_total, Dcnt, mw, out_w);
  hipLaunchKernelGGL(k_output, dim3(8192), dim3(256), 0, stream,
                     (const float4*)x, mw, (float4*)out);
}